// Round 8
// baseline (230.862 us; speedup 1.0000x reference)
//
#include <hip/hip_runtime.h>
#include <math.h>

#ifndef M_PI
#define M_PI 3.14159265358979323846
#endif

#define BB 8
#define NN 512
#define KK 64
#define GG 4096
#define MM 100

// ---------------- workspace layout (byte offsets) ----------------
#define SZ_VD    (BB*GG*8u)
#define OFF_VD   0u
#define SZ_VM    (BB*MM*8u)
#define OFF_VM   (OFF_VD + SZ_VD)
#define SZ_AD    (BB*MM*MM*8u)
#define OFF_AD   (OFF_VM + SZ_VM)
#define OFF_MIND (OFF_AD + SZ_AD)

// ---------------- output layout (float element offsets) ----------------
#define OUT_M  0
#define OUT_V  (BB*NN*GG)               // 16,777,216
#define OUT_A  (OUT_V + BB*GG)          // 16,809,984
#define OUT_B  (OUT_A + BB*MM*MM)      // 16,889,984
#define OUT_MI (OUT_B + BB*MM*MM)      // 16,969,984

// ---------------- m-unit allocation across dispatches ----------------
// Wall-time model from r1-r7: dispatch time = cycles/clock and clock tracks
// chip activity; the dependency-free m-writes are the clock-keeper. Spread
// them, with the big share covering the serial inversion tail.
#define MU_VP 4096            // with k_vpart   (units 0..4095)
#define MU_AS 2048            // with k_Asel    (units 4096..6143)
#define MU_IV 10240           // with k_inv_m   (units 6144..16383)

__device__ __forceinline__ void m_one_unit(const float* __restrict__ pts,
                                           float* __restrict__ out, int u) {
  int t = u*256 + (int)threadIdx.x;
  int e = t << 2;
  int img = e >> 21;
  int rem = e & ((1 << 21) - 1);
  int n = rem >> 12;
  int g = rem & 4095;
  int iy = g >> 6, ix = g & 63;         // e%4==0 -> ix%4==0
  const float CM = (float)(1.0/(2.0*M_PI*128.0));
  float x = pts[(img*NN + n)*2 + 0];
  float y = pts[(img*NN + n)*2 + 1];
  float dy = y - (8.0f*iy + 4.0f);
  float ey = __expf(dy*dy*(-0.5f/128.0f));
  float4 r;
  float dx0 = x - (8.0f*ix + 4.0f);
  float dx1 = x - (8.0f*(ix+1) + 4.0f);
  float dx2 = x - (8.0f*(ix+2) + 4.0f);
  float dx3 = x - (8.0f*(ix+3) + 4.0f);
  r.x = ey*__expf(dx0*dx0*(-0.5f/128.0f))*CM;
  r.y = ey*__expf(dx1*dx1*(-0.5f/128.0f))*CM;
  r.z = ey*__expf(dx2*dx2*(-0.5f/128.0f))*CM;
  r.w = ey*__expf(dx3*dx3*(-0.5f/128.0f))*CM;
  *reinterpret_cast<float4*>(&out[OUT_M + e]) = r;
}

__device__ __forceinline__ float flt_readlane(float v, int l) {
  return __int_as_float(__builtin_amdgcn_readlane(__float_as_int(v), l));
}

// ============ K2: v — two 64x64 matmuls, FULL-K + background m blocks ============
__global__ __launch_bounds__(256) void k_vpart(const float* __restrict__ pts,
                                               double* __restrict__ vd,
                                               float* __restrict__ out) {
  __shared__ double sEy2[16][66], sEx2[16][66], sEy3[16][66], sEx3[16][66];
  __shared__ float px[NN], py[NN];
  int bid = blockIdx.x;                 // img*16 + tile  |  m blocks
  if (bid >= BB*16) { m_one_unit(pts, out, bid - BB*16 + 0); return; }
  int tile = bid & 15;
  int img = bid >> 4;
  int iy0 = (tile >> 2) << 4;
  int ix0 = (tile & 3) << 4;
  int tx = threadIdx.x & 15, ty = threadIdx.x >> 4;
  for (int s = threadIdx.x; s < NN; s += 256) {
    px[s] = pts[(img*NN + s)*2 + 0];
    py[s] = pts[(img*NN + s)*2 + 1];
  }
  double aV = 0.0, aM = 0.0;
  for (int kc = 0; kc < 8; ++kc) {
    int nb = kc << 6;
    __syncthreads();                    // WAR on LDS (and px/py ready on kc=0)
    for (int s = threadIdx.x; s < 16*64; s += 256) {
      int row = s >> 6, n = s & 63;
      int nn = nb + n;
      double y = (double)py[nn];
      double cy = 8.0*(iy0 + row) + 4.0;
      double dy = y - cy, dy2 = dy*dy;
      sEy2[row][n] = exp(dy2*(-0.5/96.0));
      sEy3[row][n] = exp(dy2*(-1.0/128.0));
      double x = (double)px[nn];
      double cx = 8.0*(ix0 + row) + 4.0;
      double dx = x - cx, dx2 = dx*dx;
      sEx2[row][n] = exp(dx2*(-0.5/96.0));
      sEx3[row][n] = exp(dx2*(-1.0/128.0));
    }
    __syncthreads();
    #pragma unroll 8
    for (int n = 0; n < 64; ++n) {
      aV += sEy2[ty][n]*sEx2[tx][n];
      aM += sEy3[ty][n]*sEx3[tx][n];
    }
  }
  const double CTV = 1.0/((2.0*M_PI*96.0)*(2.0*M_PI*128.0));
  const double CM2 = 1.0/((2.0*M_PI*128.0)*(2.0*M_PI*128.0));
  vd[img*GG + (iy0 + ty)*KK + ix0 + tx] = CTV*aV - CM2*aM;
}

// ---------------- LDS union for fused select+A ----------------
union AselU {
  struct {
    unsigned long long ku[GG];                 // 32 KB sortable keys
    unsigned int hist4[4][256];                // per-wave histogram copies
    unsigned int suf[257];                     // suffix sums (+guard)
    unsigned long long sPrefPlaced, sMaskHi;
    unsigned int sRem, sPickB, sPickRem, sCGt, sCEq;
    int tie[128];
  } se;                                        // 38,440 B
  struct {
    float sxi[16][130], syi[16][130], sti[16][130];
    float sxj[16][130], syj[16][130], stj[16][130];
    float px[NN], py[NN];
    float cxi[16], cyi[16], cxj[16], cyj[16];
  } ka;                                        // 54,272 B (max)
};

// ---------------- bitonic sort of 128 ints ascending (shared array) ----------------
__device__ __forceinline__ void bitonic128(int* a, int tid) {
  for (int kk = 2; kk <= 128; kk <<= 1)
    for (int jj = kk >> 1; jj > 0; jj >>= 1) {
      if (tid < 128) {
        int p = tid ^ jj;
        if (p > tid) {
          int x = a[tid], y = a[p];
          bool up = ((tid & kk) == 0);
          if (up ? (x > y) : (x < y)) { a[tid] = y; a[p] = x; }
        }
      }
      __syncthreads();
    }
}

// ============ K34: FUSED top-100 radix select + A assembly + background m ============
// r7 model: k_select was a whole dispatch (+gap) whose result is a pure
// function of vd. Every A-block re-derives its image's top-100 in-LDS
// (deterministic: set {k>T} is atomic-order independent; ties resolved by
// sorted smallest-index). 28x redundant per image but blocks are parallel
// on an idle machine; kills one dispatch + the global minds round-trip.
// Only tile-0 blocks emit OUT_V / OUT_MI / vm.
__global__ __launch_bounds__(256) void k_Asel(const float* __restrict__ pts,
                                              const double* __restrict__ vd,
                                              float* __restrict__ out,
                                              double* __restrict__ ad,
                                              double* __restrict__ vm) {
  __shared__ AselU u;
  __shared__ int selFinal[128];         // survives the union switch se -> ka
  int bid = blockIdx.x;                 // img*28 + tri-tile  |  m blocks
  if (bid >= BB*28) { m_one_unit(pts, out, bid - BB*28 + MU_VP); return; }
  int img = bid / 28;
  int tile = bid - img*28;
  bool tile0 = (tile == 0);
  int tid = threadIdx.x;
  int wv = tid >> 6;

  // ================= select phase (LDS as u.se) =================
  for (int t = 0; t < 16; ++t) {
    int g = t*256 + tid;
    double v = vd[img*GG + g];
    if (tile0) out[OUT_V + img*GG + g] = (float)fmax(v, 1e-6);
    long long w = __double_as_longlong(v);
    unsigned long long k = (w < 0) ? ~(unsigned long long)w
                                   : ((unsigned long long)w | 0x8000000000000000ull);
    u.se.ku[g] = k;
  }
  if (tid == 0) {
    u.se.sRem = 100; u.se.sPrefPlaced = 0ull; u.se.sMaskHi = 0ull;
    u.se.sCGt = 0; u.se.sCEq = 0; u.se.suf[256] = 0;
  }
  for (int shift = 56; shift >= 0; shift -= 8) {
    for (int c = 0; c < 4; ++c) u.se.hist4[c][tid] = 0;
    __syncthreads();                    // ku ready / hist zeroed / state stable
    unsigned long long maskHi = u.se.sMaskHi, prefP = u.se.sPrefPlaced;
    for (int t = 0; t < 16; ++t) {
      int g = t*256 + tid;
      unsigned long long k = u.se.ku[g];
      if ((k & maskHi) == prefP) {
        unsigned d = (unsigned)((k >> shift) & 255ull);
        atomicAdd(&u.se.hist4[wv][d], 1u);
      }
    }
    __syncthreads();
    u.se.suf[tid] = u.se.hist4[0][tid] + u.se.hist4[1][tid]
                  + u.se.hist4[2][tid] + u.se.hist4[3][tid];
    __syncthreads();
    for (int off = 1; off < 256; off <<= 1) {   // Hillis-Steele suffix sum
      unsigned add = (tid + off < 256) ? u.se.suf[tid + off] : 0u;
      __syncthreads();
      u.se.suf[tid] += add;
      __syncthreads();
    }
    unsigned rem = u.se.sRem;
    unsigned sgt = (tid < 255) ? u.se.suf[tid + 1] : 0u;
    if (u.se.suf[tid] >= rem && sgt < rem) { u.se.sPickB = (unsigned)tid; u.se.sPickRem = rem - sgt; }
    __syncthreads();
    if (tid == 0) {
      u.se.sPrefPlaced |= ((unsigned long long)u.se.sPickB) << shift;
      u.se.sMaskHi     |= (255ull << shift);
      u.se.sRem = u.se.sPickRem;
    }
    __syncthreads();
  }
  unsigned long long T = u.se.sPrefPlaced;      // exact 100th-largest key
  for (int t = 0; t < 16; ++t) {
    int g = t*256 + tid;
    unsigned long long k = u.se.ku[g];
    if (k > T) {
      unsigned p = atomicAdd(&u.se.sCGt, 1u);   // p <= 98 always
      selFinal[p] = g;
    } else if (k == T) {
      unsigned p = atomicAdd(&u.se.sCEq, 1u);
      if (p < 128) u.se.tie[p] = g;
    }
  }
  __syncthreads();
  unsigned cgt = u.se.sCGt, ceq = u.se.sCEq, r = u.se.sRem;
  if (tid < 128 && tid >= (int)((ceq < 128u) ? ceq : 128u)) u.se.tie[tid] = 0x7fffffff;
  __syncthreads();
  bitonic128(u.se.tie, tid);                     // ties ascending by index
  if (tid < (int)r) selFinal[cgt + tid] = u.se.tie[tid];
  if (tid >= MM && tid < 128) selFinal[tid] = 0x7fffffff;
  __syncthreads();
  bitonic128(selFinal, tid);                     // final Minds ascending
  if (tile0 && tid < MM) {
    int mi = selFinal[tid];
    out[OUT_MI + img*MM + tid] = (float)mi;      // whole out buffer is float32
    vm[img*MM + tid] = fmax(vd[img*GG + mi], 1e-6) + 1e-10;
  }
  __syncthreads();                               // done with u.se before ka overwrite

  // ================= A phase (LDS as u.ka) =================
  int it = 0, trem = tile;
  while (trem >= 7 - it) { trem -= 7 - it; ++it; }
  int jt = it + trem;
  int i0 = it*16, j0 = jt*16;
  int tj = tid & 15, ti = tid >> 4;
  int i = i0 + ti, j = j0 + tj;
  const float CM = (float)(1.0/(2.0*M_PI*128.0));
  const float C1 = (float)(1.0/(2.0*M_PI*128.0));   // g1 scale (2*pi*2*sigma2)
  const float C2 = (float)(1.0/(2.0*M_PI*96.0));    // h scale (2*pi*s2)
  for (int s = tid; s < NN; s += 256) {
    u.ka.px[s] = pts[(img*NN + s)*2 + 0];
    u.ka.py[s] = pts[(img*NN + s)*2 + 1];
  }
  if (tid < 16) {
    int gi = i0 + tid; if (gi > 99) gi = 99;
    int mi = selFinal[gi];
    u.ka.cxi[tid] = 8.0f*(mi & 63) + 4.0f;
    u.ka.cyi[tid] = 8.0f*(mi >> 6) + 4.0f;
  } else if (tid < 32) {
    int rr = tid - 16;
    int gj = j0 + rr; if (gj > 99) gj = 99;
    int mj = selFinal[gj];
    u.ka.cxj[rr] = 8.0f*(mj & 63) + 4.0f;
    u.ka.cyj[rr] = 8.0f*(mj >> 6) + 4.0f;
  }
  float aV = 0.0f, aM = 0.0f;
  for (int nc = 0; nc < NN; nc += 128) {
    __syncthreads();
    for (int s = tid; s < 16*128; s += 256) {
      int row = s >> 7, n = s & 127;
      float x = u.ka.px[nc + n], y = u.ka.py[nc + n];
      float fxi = x - u.ka.cxi[row], fyi = y - u.ka.cyi[row];
      u.ka.sxi[row][n] = fxi; u.ka.syi[row][n] = fyi;
      u.ka.sti[row][n] = __expf((fxi*fxi + fyi*fyi)*(-0.5f/128.0f))*CM;
      float fxj = x - u.ka.cxj[row], fyj = y - u.ka.cyj[row];
      u.ka.sxj[row][n] = fxj; u.ka.syj[row][n] = fyj;
      u.ka.stj[row][n] = __expf((fxj*fxj + fyj*fyj)*(-0.5f/128.0f))*CM;
    }
    __syncthreads();
    #pragma unroll 4
    for (int n = 0; n < 128; ++n) {
      float xi = u.ka.sxi[ti][n], yi = u.ka.syi[ti][n], tii = u.ka.sti[ti][n];
      float xj = u.ka.sxj[tj][n], yj = u.ka.syj[tj][n], tjj = u.ka.stj[tj][n];
      float ddx = xj - xi, ddy = yj - yi;
      float df = ddx*ddx + ddy*ddy;
      float sx = 0.5f*(xi + xj), sy = 0.5f*(yi + yj);
      float af = sx*sx + sy*sy;
      float g1 = __expf(df*(-0.5f/128.0f))*C1;
      float h  = __expf(af*(-0.5f/96.0f))*C2;
      aV += g1 + g1*h;
      aM += tii*tjj;
    }
  }
  if (i < 100 && j < 100) {
    double val = (i == j) ? 1e-10 : ((double)aV - (double)aM);
    out[OUT_A + (img*MM + i)*MM + j] = (float)val;
    ad[(img*MM + i)*MM + j] = val;
    if (it != jt) {                     // mirror (diag tiles cover both in-tile)
      out[OUT_A + (img*MM + j)*MM + i] = (float)val;
      ad[(img*MM + j)*MM + i] = val;
    }
  }
}

// ============ K5: FP32 GJ inversion (blocks 0..7) + remaining m blocks ============
__global__ __launch_bounds__(256)
void k_inv_m(const double* __restrict__ ad,
             const double* __restrict__ vm,
             const float* __restrict__ pts,
             float* __restrict__ out) {
  __shared__ float S[128*17];           //  8,704 B
  __shared__ float Pr[16*113];          //  7,232 B
  __shared__ float svm[112];            //    448 B  -> total 16,384 B
  if (blockIdx.x >= BB) {
    m_one_unit(pts, out, (int)blockIdx.x - BB + MU_VP + MU_AS);
    return;
  }
  // ---- inversion part: no-pivot blocked fp32 GJ (SPD), Bm = Dv^{-1} - (A+Dv)^{-1}
  int img = blockIdx.x;
  int tx = threadIdx.x & 15, ty = threadIdx.x >> 4;   // ty in [0,16)
  float C[7][7];
  if (threadIdx.x < 100) svm[threadIdx.x] = (float)vm[img*MM + threadIdx.x];
  // init C = A + diag(vM); rows/cols >= 100 -> 0
  #pragma unroll
  for (int a = 0; a < 7; ++a) {
    int r = ty + 16*a;
    #pragma unroll
    for (int b = 0; b < 7; ++b) {
      int j = tx + 16*b;
      float v2 = (r < 100 && j < 100) ? (float)ad[(img*MM + r)*MM + j] : 0.0f;
      if (r == j && r < 100) v2 += (float)vm[img*MM + r];
      C[a][b] = v2;
    }
  }
  for (int p = 0; p < 7; ++p) {
    int k0 = p*16;
    int nbp = (p == 6) ? 4 : 16;
    // ---- P1: stage panel-col strip S + panel rows Pr (phase-start values)
    #pragma unroll
    for (int a = 0; a < 7; ++a) {
      int r = ty + 16*a;
      float val = 0.0f;
      #pragma unroll
      for (int b = 0; b < 7; ++b) if (b == p) val = C[a][b];
      S[r*17 + tx] = (r < 100 && tx < nbp) ? val : 0.0f;
    }
    {
      float pv[7];
      #pragma unroll
      for (int b = 0; b < 7; ++b) pv[b] = 0.0f;
      #pragma unroll
      for (int a = 0; a < 7; ++a) {
        #pragma unroll
        for (int b = 0; b < 7; ++b) if (a == p) pv[b] = C[a][b];
      }
      #pragma unroll
      for (int b = 0; b < 7; ++b) Pr[ty*113 + tx + 16*b] = pv[b];
    }
    __syncthreads();                                   // B1
    // ---- P2: wave 0 register-resident strip factorization (no pivoting)
    if (threadIdx.x < 64) {
      int lane = threadIdx.x;
      float P0[16], P1[16];
      #pragma unroll
      for (int c = 0; c < 16; ++c) {
        P0[c] = S[lane*17 + c];
        P1[c] = (lane + 64 < 112) ? S[(lane + 64)*17 + c] : 0.0f;
      }
      #pragma unroll
      for (int kk = 0; kk < 16; ++kk) {
        if (kk < nbp) {
          int kg = k0 + kk;
          int r1 = lane + 64;
          bool khigh = kg >= 64; int kl = kg & 63;
          float pivinv = 1.0f / flt_readlane(khigh ? P1[kk] : P0[kk], kl);
          float pr[16];
          #pragma unroll
          for (int c = 0; c < 16; ++c) {
            float pv = flt_readlane(khigh ? P1[c] : P0[c], kl);
            pr[c] = (c == kk) ? pivinv : pv*pivinv;
          }
          {
            float f = P0[kk];
            if (lane == kg) {
              #pragma unroll
              for (int c = 0; c < 16; ++c) P0[c] = pr[c];
            } else {
              #pragma unroll
              for (int c = 0; c < 16; ++c) P0[c] = ((c == kk) ? 0.0f : P0[c]) - f*pr[c];
            }
          }
          {
            float f = P1[kk];
            if (r1 == kg) {
              #pragma unroll
              for (int c = 0; c < 16; ++c) P1[c] = pr[c];
            } else {
              #pragma unroll
              for (int c = 0; c < 16; ++c) P1[c] = ((c == kk) ? 0.0f : P1[c]) - f*pr[c];
            }
          }
        }
      }
      #pragma unroll
      for (int c = 0; c < 16; ++c) {
        S[lane*17 + c] = P0[c];
        if (lane + 64 < 112) S[(lane + 64)*17 + c] = P1[c];
      }
    }
    __syncthreads();                                   // B2
    // ---- P3: mask C in REGISTERS, trailing rank-16 update, panel-col writeback
    #pragma unroll
    for (int a = 0; a < 7; ++a) {
      int r = ty + 16*a;
      bool prow_ = (r >= k0) && (r < k0 + 16);
      #pragma unroll
      for (int b = 0; b < 7; ++b) {
        if (r >= 100 || b == p || prow_) C[a][b] = 0.0f;
      }
    }
    #pragma unroll 4
    for (int t = 0; t < 16; ++t) {
      bool tok = (t < nbp);
      float bt[7], sa[7];
      #pragma unroll
      for (int b = 0; b < 7; ++b) bt[b] = tok ? Pr[t*113 + tx + 16*b] : 0.0f;
      #pragma unroll
      for (int a = 0; a < 7; ++a) sa[a] = S[(ty + 16*a)*17 + t];
      #pragma unroll
      for (int a = 0; a < 7; ++a)
        #pragma unroll
        for (int b = 0; b < 7; ++b) C[a][b] += sa[a]*bt[b];
    }
    #pragma unroll
    for (int a = 0; a < 7; ++a) {
      int r = ty + 16*a;
      float sval = S[r*17 + tx];
      #pragma unroll
      for (int b = 0; b < 7; ++b) if (b == p) C[a][b] = sval;
    }
    __syncthreads();                                   // B3 (WAR on S/Pr)
  }
  // Bm = Dv^{-1} - X
  #pragma unroll
  for (int a = 0; a < 7; ++a) {
    int r = ty + 16*a; if (r >= 100) continue;
    float dinv = 1.0f / svm[r];
    #pragma unroll
    for (int b = 0; b < 7; ++b) {
      int c = tx + 16*b; if (c >= 100) continue;
      float val = ((c == r) ? dinv : 0.0f) - C[a][b];
      out[OUT_B + (img*MM + r)*MM + c] = val;
    }
  }
}

extern "C" void kernel_launch(void* const* d_in, const int* in_sizes, int n_in,
                              void* d_out, int out_size, void* d_ws, size_t ws_size,
                              hipStream_t stream) {
  const float* pts = (const float*)d_in[0];
  float* out = (float*)d_out;
  char* ws = (char*)d_ws;
  double* vd  = (double*)(ws + OFF_VD);
  double* vmd = (double*)(ws + OFF_VM);
  double* ad  = (double*)(ws + OFF_AD);

  hipLaunchKernelGGL(k_vpart, dim3(BB*16 + MU_VP), dim3(256), 0, stream, pts, vd, out);
  hipLaunchKernelGGL(k_Asel, dim3(BB*28 + MU_AS), dim3(256), 0, stream, pts, vd, out, ad, vmd);
  hipLaunchKernelGGL(k_inv_m, dim3(BB + MU_IV), dim3(256), 0, stream, ad, vmd, pts, out);
}

// Round 9
// 211.649 us; speedup vs baseline: 1.0908x; 1.0908x over previous
//
#include <hip/hip_runtime.h>
#include <math.h>

#ifndef M_PI
#define M_PI 3.14159265358979323846
#endif

#define BB 8
#define NN 512
#define KK 64
#define GG 4096
#define MM 100

// ---------------- workspace layout (byte offsets) ----------------
// vd / vm / ad are fp32 now (selection is fp32-exact; inversion was already fp32)
#define SZ_VD    (BB*GG*4u)
#define OFF_VD   0u
#define SZ_VM    (BB*MM*4u)
#define OFF_VM   (OFF_VD + SZ_VD)
#define SZ_AD    (BB*MM*MM*4u)
#define OFF_AD   (OFF_VM + SZ_VM)

// ---------------- output layout (float element offsets) ----------------
#define OUT_M  0
#define OUT_V  (BB*NN*GG)               // 16,777,216
#define OUT_A  (OUT_V + BB*GG)          // 16,809,984
#define OUT_B  (OUT_A + BB*MM*MM)      // 16,889,984
#define OUT_MI (OUT_B + BB*MM*MM)      // 16,969,984

// ---------------- m-unit allocation across dispatches ----------------
#define MU_VP 4096            // with k_vpart   (units 0..4095)
#define MU_AS 2048            // with k_Asel    (units 4096..6143)
#define MU_IV 10240           // with k_inv_m   (units 6144..16383)

__device__ __forceinline__ void m_one_unit(const float* __restrict__ pts,
                                           float* __restrict__ out, int u) {
  int t = u*256 + (int)threadIdx.x;
  int e = t << 2;
  int img = e >> 21;
  int rem = e & ((1 << 21) - 1);
  int n = rem >> 12;
  int g = rem & 4095;
  int iy = g >> 6, ix = g & 63;         // e%4==0 -> ix%4==0
  const float CM = (float)(1.0/(2.0*M_PI*128.0));
  float x = pts[(img*NN + n)*2 + 0];
  float y = pts[(img*NN + n)*2 + 1];
  float dy = y - (8.0f*iy + 4.0f);
  float ey = __expf(dy*dy*(-0.5f/128.0f));
  float4 r;
  float dx0 = x - (8.0f*ix + 4.0f);
  float dx1 = x - (8.0f*(ix+1) + 4.0f);
  float dx2 = x - (8.0f*(ix+2) + 4.0f);
  float dx3 = x - (8.0f*(ix+3) + 4.0f);
  r.x = ey*__expf(dx0*dx0*(-0.5f/128.0f))*CM;
  r.y = ey*__expf(dx1*dx1*(-0.5f/128.0f))*CM;
  r.z = ey*__expf(dx2*dx2*(-0.5f/128.0f))*CM;
  r.w = ey*__expf(dx3*dx3*(-0.5f/128.0f))*CM;
  *reinterpret_cast<float4*>(&out[OUT_M + e]) = r;
}

__device__ __forceinline__ float flt_readlane(float v, int l) {
  return __int_as_float(__builtin_amdgcn_readlane(__float_as_int(v), l));
}

// ============ K2: v — two 64x64 matmuls (fp64 accum, fp32 store) + m blocks ============
__global__ __launch_bounds__(256) void k_vpart(const float* __restrict__ pts,
                                               float* __restrict__ vd,
                                               float* __restrict__ out) {
  __shared__ double sEy2[16][66], sEx2[16][66], sEy3[16][66], sEx3[16][66];
  __shared__ float px[NN], py[NN];
  int bid = blockIdx.x;                 // img*16 + tile  |  m blocks
  if (bid >= BB*16) { m_one_unit(pts, out, bid - BB*16 + 0); return; }
  int tile = bid & 15;
  int img = bid >> 4;
  int iy0 = (tile >> 2) << 4;
  int ix0 = (tile & 3) << 4;
  int tx = threadIdx.x & 15, ty = threadIdx.x >> 4;
  for (int s = threadIdx.x; s < NN; s += 256) {
    px[s] = pts[(img*NN + s)*2 + 0];
    py[s] = pts[(img*NN + s)*2 + 1];
  }
  double aV = 0.0, aM = 0.0;
  for (int kc = 0; kc < 8; ++kc) {
    int nb = kc << 6;
    __syncthreads();                    // WAR on LDS (and px/py ready on kc=0)
    for (int s = threadIdx.x; s < 16*64; s += 256) {
      int row = s >> 6, n = s & 63;
      int nn = nb + n;
      double y = (double)py[nn];
      double cy = 8.0*(iy0 + row) + 4.0;
      double dy = y - cy, dy2 = dy*dy;
      sEy2[row][n] = exp(dy2*(-0.5/96.0));
      sEy3[row][n] = exp(dy2*(-1.0/128.0));
      double x = (double)px[nn];
      double cx = 8.0*(ix0 + row) + 4.0;
      double dx = x - cx, dx2 = dx*dx;
      sEx2[row][n] = exp(dx2*(-0.5/96.0));
      sEx3[row][n] = exp(dx2*(-1.0/128.0));
    }
    __syncthreads();
    #pragma unroll 8
    for (int n = 0; n < 64; ++n) {
      aV += sEy2[ty][n]*sEx2[tx][n];
      aM += sEy3[ty][n]*sEx3[tx][n];
    }
  }
  const double CTV = 1.0/((2.0*M_PI*96.0)*(2.0*M_PI*128.0));
  const double CM2 = 1.0/((2.0*M_PI*128.0)*(2.0*M_PI*128.0));
  vd[img*GG + (iy0 + ty)*KK + ix0 + tx] = (float)(CTV*aV - CM2*aM);
}

// ---------------- LDS union for fused select+A ----------------
union AselU {
  struct {
    unsigned int ku[GG];                       // 16 KB fp32 sortable keys
    unsigned int hist4[4][256];                // per-wave histogram copies
    unsigned int wq[4];                        // wave totals for suffix scan
    unsigned int sPref, sMask;
    unsigned int sRem, sPickB, sPickRem, sCGt, sCEq;
    int tie[128];
  } se;                                        // ~21 KB
  struct {
    float sxi[16][130], syi[16][130], sti[16][130];
    float sxj[16][130], syj[16][130], stj[16][130];
    float px[NN], py[NN];
    float cxi[16], cyi[16], cxj[16], cyj[16];
  } ka;                                        // 54,272 B (max)
};

// ---------------- bitonic sort of 128 ints ascending (shared array) ----------------
__device__ __forceinline__ void bitonic128(int* a, int tid) {
  for (int kk = 2; kk <= 128; kk <<= 1)
    for (int jj = kk >> 1; jj > 0; jj >>= 1) {
      if (tid < 128) {
        int p = tid ^ jj;
        if (p > tid) {
          int x = a[tid], y = a[p];
          bool up = ((tid & kk) == 0);
          if (up ? (x > y) : (x < y)) { a[tid] = y; a[p] = x; }
        }
      }
      __syncthreads();
    }
}

// ============ K34: FUSED fp32 top-100 radix select + A assembly + m blocks ============
// r8 post-mortem: per-block select (8 fp64 passes, ~170 barriers) cost what the
// killed dispatch saved. This version: fp32 keys -> 4 passes (ref argsorts
// FLOAT32 v anyway; monotone cast + smallest-index tie-break == stable
// argsort(-v) semantics), and a shfl-based wave suffix scan (~5 barriers/pass
// instead of ~21). Select phase ~3x cheaper.
__global__ __launch_bounds__(256) void k_Asel(const float* __restrict__ pts,
                                              const float* __restrict__ vd,
                                              float* __restrict__ out,
                                              float* __restrict__ ad,
                                              float* __restrict__ vm) {
  __shared__ AselU u;
  __shared__ int selFinal[128];         // survives the union switch se -> ka
  int bid = blockIdx.x;                 // img*28 + tri-tile  |  m blocks
  if (bid >= BB*28) { m_one_unit(pts, out, bid - BB*28 + MU_VP); return; }
  int img = bid / 28;
  int tile = bid - img*28;
  bool tile0 = (tile == 0);
  int tid = threadIdx.x;
  int wv = tid >> 6;
  int lane = tid & 63;

  // ================= select phase (LDS as u.se) =================
  for (int t = 0; t < 16; ++t) {
    int g = t*256 + tid;
    float v = vd[img*GG + g];
    if (tile0) out[OUT_V + img*GG + g] = fmaxf(v, 1e-6f);
    int w = __float_as_int(v);
    u.se.ku[g] = (w < 0) ? ~(unsigned)w : ((unsigned)w | 0x80000000u);
  }
  if (tid == 0) {
    u.se.sRem = 100; u.se.sPref = 0u; u.se.sMask = 0u;
    u.se.sCGt = 0; u.se.sCEq = 0;
  }
  // ---- 4 radix passes, MSB first ----
  for (int shift = 24; shift >= 0; shift -= 8) {
    for (int c = 0; c < 4; ++c) u.se.hist4[c][tid] = 0;
    __syncthreads();                    // ku/state ready, hist zeroed
    unsigned mask = u.se.sMask, pref = u.se.sPref;
    for (int t = 0; t < 16; ++t) {
      unsigned k = u.se.ku[t*256 + tid];
      if ((k & mask) == pref)
        atomicAdd(&u.se.hist4[wv][(k >> shift) & 255u], 1u);
    }
    __syncthreads();
    unsigned tot = u.se.hist4[0][tid] + u.se.hist4[1][tid]
                 + u.se.hist4[2][tid] + u.se.hist4[3][tid];
    // wave-level inclusive SUFFIX scan over the 64 bins this wave owns
    unsigned val = tot;
    #pragma unroll
    for (int off = 1; off < 64; off <<= 1) {
      unsigned o = (unsigned)__shfl_down((int)val, off);
      if (lane + off < 64) val += o;
    }
    if (lane == 0) u.se.wq[wv] = val;   // whole-wave total
    __syncthreads();
    unsigned suf = val;                 // + totals of higher waves (higher digits)
    for (int w2 = wv + 1; w2 < 4; ++w2) suf += u.se.wq[w2];
    unsigned rem = u.se.sRem;
    unsigned sgt = suf - tot;           // count with digit strictly greater
    if (suf >= rem && sgt < rem) { u.se.sPickB = (unsigned)tid; u.se.sPickRem = rem - sgt; }
    __syncthreads();
    if (tid == 0) {
      u.se.sPref |= u.se.sPickB << shift;
      u.se.sMask |= 255u << shift;
      u.se.sRem   = u.se.sPickRem;
    }
    __syncthreads();
  }
  // ---- collect: all k > T, plus r smallest-index ties (k == T) ----
  unsigned T = u.se.sPref;              // exact 100th-largest fp32 key
  for (int t = 0; t < 16; ++t) {
    int g = t*256 + tid;
    unsigned k = u.se.ku[g];
    if (k > T) {
      unsigned p = atomicAdd(&u.se.sCGt, 1u);   // p <= 98 always
      selFinal[p] = g;
    } else if (k == T) {
      unsigned p = atomicAdd(&u.se.sCEq, 1u);
      if (p < 128) u.se.tie[p] = g;     // >128 exact-equal boundary: pathological
    }
  }
  __syncthreads();
  unsigned cgt = u.se.sCGt, ceq = u.se.sCEq, r = u.se.sRem;
  if (tid < 128 && tid >= (int)((ceq < 128u) ? ceq : 128u)) u.se.tie[tid] = 0x7fffffff;
  __syncthreads();
  bitonic128(u.se.tie, tid);                     // ties ascending by index
  if (tid < (int)r) selFinal[cgt + tid] = u.se.tie[tid];
  if (tid >= MM && tid < 128) selFinal[tid] = 0x7fffffff;
  __syncthreads();
  bitonic128(selFinal, tid);                     // final Minds ascending
  if (tile0 && tid < MM) {
    int mi = selFinal[tid];
    out[OUT_MI + img*MM + tid] = (float)mi;      // whole out buffer is float32
    vm[img*MM + tid] = fmaxf(vd[img*GG + mi], 1e-6f) + 1e-10f;  // ref does this in fp32
  }
  __syncthreads();                               // done with u.se before ka overwrite

  // ================= A phase (LDS as u.ka) =================
  int it = 0, trem = tile;
  while (trem >= 7 - it) { trem -= 7 - it; ++it; }
  int jt = it + trem;
  int i0 = it*16, j0 = jt*16;
  int tj = tid & 15, ti = tid >> 4;
  int i = i0 + ti, j = j0 + tj;
  const float CM = (float)(1.0/(2.0*M_PI*128.0));
  const float C1 = (float)(1.0/(2.0*M_PI*128.0));   // g1 scale (2*pi*2*sigma2)
  const float C2 = (float)(1.0/(2.0*M_PI*96.0));    // h scale (2*pi*s2)
  for (int s = tid; s < NN; s += 256) {
    u.ka.px[s] = pts[(img*NN + s)*2 + 0];
    u.ka.py[s] = pts[(img*NN + s)*2 + 1];
  }
  if (tid < 16) {
    int gi = i0 + tid; if (gi > 99) gi = 99;
    int mi = selFinal[gi];
    u.ka.cxi[tid] = 8.0f*(mi & 63) + 4.0f;
    u.ka.cyi[tid] = 8.0f*(mi >> 6) + 4.0f;
  } else if (tid < 32) {
    int rr = tid - 16;
    int gj = j0 + rr; if (gj > 99) gj = 99;
    int mj = selFinal[gj];
    u.ka.cxj[rr] = 8.0f*(mj & 63) + 4.0f;
    u.ka.cyj[rr] = 8.0f*(mj >> 6) + 4.0f;
  }
  float aV = 0.0f, aM = 0.0f;
  for (int nc = 0; nc < NN; nc += 128) {
    __syncthreads();
    for (int s = tid; s < 16*128; s += 256) {
      int row = s >> 7, n = s & 127;
      float x = u.ka.px[nc + n], y = u.ka.py[nc + n];
      float fxi = x - u.ka.cxi[row], fyi = y - u.ka.cyi[row];
      u.ka.sxi[row][n] = fxi; u.ka.syi[row][n] = fyi;
      u.ka.sti[row][n] = __expf((fxi*fxi + fyi*fyi)*(-0.5f/128.0f))*CM;
      float fxj = x - u.ka.cxj[row], fyj = y - u.ka.cyj[row];
      u.ka.sxj[row][n] = fxj; u.ka.syj[row][n] = fyj;
      u.ka.stj[row][n] = __expf((fxj*fxj + fyj*fyj)*(-0.5f/128.0f))*CM;
    }
    __syncthreads();
    #pragma unroll 4
    for (int n = 0; n < 128; ++n) {
      float xi = u.ka.sxi[ti][n], yi = u.ka.syi[ti][n], tii = u.ka.sti[ti][n];
      float xj = u.ka.sxj[tj][n], yj = u.ka.syj[tj][n], tjj = u.ka.stj[tj][n];
      float ddx = xj - xi, ddy = yj - yi;
      float df = ddx*ddx + ddy*ddy;
      float sx = 0.5f*(xi + xj), sy = 0.5f*(yi + yj);
      float af = sx*sx + sy*sy;
      float g1 = __expf(df*(-0.5f/128.0f))*C1;
      float h  = __expf(af*(-0.5f/96.0f))*C2;
      aV += g1 + g1*h;
      aM += tii*tjj;
    }
  }
  if (i < 100 && j < 100) {
    float val = (i == j) ? 1e-10f : (float)((double)aV - (double)aM);
    out[OUT_A + (img*MM + i)*MM + j] = val;
    ad[(img*MM + i)*MM + j] = val;
    if (it != jt) {                     // mirror (diag tiles cover both in-tile)
      out[OUT_A + (img*MM + j)*MM + i] = val;
      ad[(img*MM + j)*MM + i] = val;
    }
  }
}

// ============ K5: FP32 GJ inversion (blocks 0..7) + remaining m blocks ============
__global__ __launch_bounds__(256)
void k_inv_m(const float* __restrict__ ad,
             const float* __restrict__ vm,
             const float* __restrict__ pts,
             float* __restrict__ out) {
  __shared__ float S[128*17];           //  8,704 B
  __shared__ float Pr[16*113];          //  7,232 B
  __shared__ float svm[112];            //    448 B  -> total 16,384 B
  if (blockIdx.x >= BB) {
    m_one_unit(pts, out, (int)blockIdx.x - BB + MU_VP + MU_AS);
    return;
  }
  // ---- inversion part: no-pivot blocked fp32 GJ (SPD), Bm = Dv^{-1} - (A+Dv)^{-1}
  int img = blockIdx.x;
  int tx = threadIdx.x & 15, ty = threadIdx.x >> 4;   // ty in [0,16)
  float C[7][7];
  if (threadIdx.x < 100) svm[threadIdx.x] = vm[img*MM + threadIdx.x];
  // init C = A + diag(vM); rows/cols >= 100 -> 0
  #pragma unroll
  for (int a = 0; a < 7; ++a) {
    int r = ty + 16*a;
    #pragma unroll
    for (int b = 0; b < 7; ++b) {
      int j = tx + 16*b;
      float v2 = (r < 100 && j < 100) ? ad[(img*MM + r)*MM + j] : 0.0f;
      if (r == j && r < 100) v2 += vm[img*MM + r];
      C[a][b] = v2;
    }
  }
  for (int p = 0; p < 7; ++p) {
    int k0 = p*16;
    int nbp = (p == 6) ? 4 : 16;
    // ---- P1: stage panel-col strip S + panel rows Pr (phase-start values)
    #pragma unroll
    for (int a = 0; a < 7; ++a) {
      int r = ty + 16*a;
      float val = 0.0f;
      #pragma unroll
      for (int b = 0; b < 7; ++b) if (b == p) val = C[a][b];
      S[r*17 + tx] = (r < 100 && tx < nbp) ? val : 0.0f;
    }
    {
      float pv[7];
      #pragma unroll
      for (int b = 0; b < 7; ++b) pv[b] = 0.0f;
      #pragma unroll
      for (int a = 0; a < 7; ++a) {
        #pragma unroll
        for (int b = 0; b < 7; ++b) if (a == p) pv[b] = C[a][b];
      }
      #pragma unroll
      for (int b = 0; b < 7; ++b) Pr[ty*113 + tx + 16*b] = pv[b];
    }
    __syncthreads();                                   // B1
    // ---- P2: wave 0 register-resident strip factorization (no pivoting)
    if (threadIdx.x < 64) {
      int lane = threadIdx.x;
      float P0[16], P1[16];
      #pragma unroll
      for (int c = 0; c < 16; ++c) {
        P0[c] = S[lane*17 + c];
        P1[c] = (lane + 64 < 112) ? S[(lane + 64)*17 + c] : 0.0f;
      }
      #pragma unroll
      for (int kk = 0; kk < 16; ++kk) {
        if (kk < nbp) {
          int kg = k0 + kk;
          int r1 = lane + 64;
          bool khigh = kg >= 64; int kl = kg & 63;
          float pivinv = 1.0f / flt_readlane(khigh ? P1[kk] : P0[kk], kl);
          float pr[16];
          #pragma unroll
          for (int c = 0; c < 16; ++c) {
            float pv = flt_readlane(khigh ? P1[c] : P0[c], kl);
            pr[c] = (c == kk) ? pivinv : pv*pivinv;
          }
          {
            float f = P0[kk];
            if (lane == kg) {
              #pragma unroll
              for (int c = 0; c < 16; ++c) P0[c] = pr[c];
            } else {
              #pragma unroll
              for (int c = 0; c < 16; ++c) P0[c] = ((c == kk) ? 0.0f : P0[c]) - f*pr[c];
            }
          }
          {
            float f = P1[kk];
            if (r1 == kg) {
              #pragma unroll
              for (int c = 0; c < 16; ++c) P1[c] = pr[c];
            } else {
              #pragma unroll
              for (int c = 0; c < 16; ++c) P1[c] = ((c == kk) ? 0.0f : P1[c]) - f*pr[c];
            }
          }
        }
      }
      #pragma unroll
      for (int c = 0; c < 16; ++c) {
        S[lane*17 + c] = P0[c];
        if (lane + 64 < 112) S[(lane + 64)*17 + c] = P1[c];
      }
    }
    __syncthreads();                                   // B2
    // ---- P3: mask C in REGISTERS, trailing rank-16 update, panel-col writeback
    #pragma unroll
    for (int a = 0; a < 7; ++a) {
      int r = ty + 16*a;
      bool prow_ = (r >= k0) && (r < k0 + 16);
      #pragma unroll
      for (int b = 0; b < 7; ++b) {
        if (r >= 100 || b == p || prow_) C[a][b] = 0.0f;
      }
    }
    #pragma unroll 4
    for (int t = 0; t < 16; ++t) {
      bool tok = (t < nbp);
      float bt[7], sa[7];
      #pragma unroll
      for (int b = 0; b < 7; ++b) bt[b] = tok ? Pr[t*113 + tx + 16*b] : 0.0f;
      #pragma unroll
      for (int a = 0; a < 7; ++a) sa[a] = S[(ty + 16*a)*17 + t];
      #pragma unroll
      for (int a = 0; a < 7; ++a)
        #pragma unroll
        for (int b = 0; b < 7; ++b) C[a][b] += sa[a]*bt[b];
    }
    #pragma unroll
    for (int a = 0; a < 7; ++a) {
      int r = ty + 16*a;
      float sval = S[r*17 + tx];
      #pragma unroll
      for (int b = 0; b < 7; ++b) if (b == p) C[a][b] = sval;
    }
    __syncthreads();                                   // B3 (WAR on S/Pr)
  }
  // Bm = Dv^{-1} - X
  #pragma unroll
  for (int a = 0; a < 7; ++a) {
    int r = ty + 16*a; if (r >= 100) continue;
    float dinv = 1.0f / svm[r];
    #pragma unroll
    for (int b = 0; b < 7; ++b) {
      int c = tx + 16*b; if (c >= 100) continue;
      float val = ((c == r) ? dinv : 0.0f) - C[a][b];
      out[OUT_B + (img*MM + r)*MM + c] = val;
    }
  }
}

extern "C" void kernel_launch(void* const* d_in, const int* in_sizes, int n_in,
                              void* d_out, int out_size, void* d_ws, size_t ws_size,
                              hipStream_t stream) {
  const float* pts = (const float*)d_in[0];
  float* out = (float*)d_out;
  char* ws = (char*)d_ws;
  float* vd  = (float*)(ws + OFF_VD);
  float* vmd = (float*)(ws + OFF_VM);
  float* ad  = (float*)(ws + OFF_AD);

  hipLaunchKernelGGL(k_vpart, dim3(BB*16 + MU_VP), dim3(256), 0, stream, pts, vd, out);
  hipLaunchKernelGGL(k_Asel, dim3(BB*28 + MU_AS), dim3(256), 0, stream, pts, vd, out, ad, vmd);
  hipLaunchKernelGGL(k_inv_m, dim3(BB + MU_IV), dim3(256), 0, stream, ad, vmd, pts, out);
}